// Round 1
// 201.942 us; speedup vs baseline: 1.0046x; 1.0046x over previous
//
#include <hip/hip_runtime.h>
#include <math.h>

#define BLK 256
#define SBLK 1024
#define NBINS 2048
#define HREP 2
#define CSH 42
#define QMASK ((1ULL << CSH) - 1ULL)

__device__ __forceinline__ float bce_logits(float x, float t){
    return fmaxf(x, 0.f) - x * t + log1pf(expf(-fabsf(x)));
}
__device__ __forceinline__ float smooth_l1(float x){
    float ax = fabsf(x);
    return ax < 1.f ? 0.5f * x * x : ax - 0.5f;
}

// All 3 scales, one dispatch, 4 anchors/thread, block GT y-cull (culled GTs
// have IoU==0 exactly -> first-argmax/pos/neg semantics preserved).
// NEW: negatives' BCE values are binned HERE into a per-block LDS histogram
// (packed count<<42 | v*2^22), flushed with sparse global u64 atomics into
// the per-(scale,image) histogram. The 16.5 MB vals round-trip is gone.
__global__ __launch_bounds__(BLK)
void det_map_all(const float* __restrict__ pred0,
                 const float* __restrict__ pred1,
                 const float* __restrict__ pred2,
                 const float* __restrict__ gtb,   // (B,32,4)
                 const int*   __restrict__ gtl,   // (B,32)
                 unsigned long long* __restrict__ hist, // (3*B, NBINS) zeroed
                 float* __restrict__ loss_slot,   // 63*B per-block map loss
                 int*   __restrict__ pcnt_slot,   // 63*B per-block pos count
                 unsigned* __restrict__ done_cnt, // zeroed by block (0,0)
                 int B)
{
    const int b  = blockIdx.y;
    const int bx = blockIdx.x;

    const float* pred; int s, qloc, P, logW; float stride_f;
    if (bx < 48){      s=0; pred=pred0; P=16384; logW=7; stride_f= 8.f; qloc= bx      << 8; }
    else if (bx < 60){ s=1; pred=pred1; P= 4096; logW=6; stride_f=16.f; qloc=(bx-48) << 8; }
    else {             s=2; pred=pred2; P= 1024; logW=5; stride_f=32.f; qloc=(bx-60) << 8; }

    const int tid = threadIdx.x;
    const int lq  = 2*logW - 2;            // log2(P/4)
    const int Q4  = 1 << lq;
    const int a   = qloc >> lq;            // block-uniform (Q4 % 256 == 0)
    const int pix0 = (qloc - a*Q4 + tid) << 2;

    const float half = 0.5f * (float)(3 + a) * stride_f;

    // block anchor y-extent for culling
    const int pixLo = (qloc - a*Q4) << 2;
    const int y0 = pixLo >> logW, y1 = (pixLo + BLK*4 - 1) >> logW;
    const float ymin = ((float)y0 + 0.5f) * stride_f - half;
    const float ymax = ((float)y1 + 0.5f) * stride_f + half;

    __shared__ float4 sg[32];
    __shared__ float  sarea[32];
    __shared__ int    sl[32];
    __shared__ int    s_cnt;
    __shared__ unsigned long long sh_h[HREP][NBINS];   // 32 KB

    // zero the block histogram (16 u64 stores / thread)
    for (int i = tid; i < HREP * NBINS; i += BLK)
        ((unsigned long long*)sh_h)[i] = 0ULL;

    {
        bool keep = false; float4 G;
        if (tid < 32){
            G = ((const float4*)gtb)[b * 32 + tid];
            keep = (G.y < ymax) && (G.w > ymin);
        }
        unsigned long long m = __ballot(keep);
        if (tid < 64){
            if (keep){
                int idx = (int)__popcll(m & ((1ULL << tid) - 1ULL));
                sg[idx] = G;
                sarea[idx] = (G.z - G.x) * (G.w - G.y);
                sl[idx] = gtl[b * 32 + tid];
            }
            if (tid == 0) s_cnt = (int)__popcll(m);
        }
    }
    __syncthreads();
    const int cnt = s_cnt;

    const int x0 = pix0 & ((1 << logW) - 1);
    const int y  = pix0 >> logW;
    const float cy = ((float)y + 0.5f) * stride_f;
    const float Ay = cy - half, Ay2 = cy + half;
    const float area_a = (2.f * half) * (2.f * half);

    float ax[4], az[4];
    #pragma unroll
    for (int j = 0; j < 4; ++j){
        float cx = ((float)(x0 + j) + 0.5f) * stride_f;
        ax[j] = cx - half; az[j] = cx + half;
    }

    float bi[4] = {-1.f, -1.f, -1.f, -1.f};
    float bd[4] = { 1.f,  1.f,  1.f,  1.f};
    int   bg[4] = {0, 0, 0, 0};

    for (int g = 0; g < cnt; ++g){
        const float4 G = sg[g];
        const float sab = area_a + sarea[g];
        const float h = fmaxf(fminf(Ay2, G.w) - fmaxf(Ay, G.y), 0.f);
        #pragma unroll
        for (int j = 0; j < 4; ++j){
            float wdt = fmaxf(fminf(az[j], G.z) - fmaxf(ax[j], G.x), 0.f);
            float inter = wdt * h;
            float d = (sab - inter) + 1e-9f;
            if (inter * bd[j] > bi[j] * d){ bi[j] = inter; bd[j] = d; bg[j] = g; }
        }
    }

    const size_t cP = (size_t)P;
    const float* pp = pred + ((size_t)b * 24 + (size_t)a * 8) * cP + (size_t)pix0;
    const float4 p4v = *(const float4*)(pp + 4 * cP);
    const float p4a[4] = {p4v.x, p4v.y, p4v.z, p4v.w};

    const int rep = tid & (HREP - 1);
    float loss = 0.f; int pc = 0;
    #pragma unroll
    for (int j = 0; j < 4; ++j){
        const bool pos = 2.f * bi[j] >= bd[j];    // iou >= 0.5
        const bool neg = bi[j] < 0.4f * bd[j];    // iou <  0.4
        if (neg){
            float v = bce_logits(p4a[j], 0.f);
            int bin = min((int)(v * 512.f), NBINS - 1);
            unsigned long long pq = (1ULL << CSH) |
                (unsigned long long)(unsigned)(int)(v * 4194304.f);   // v*2^22
            atomicAdd(&sh_h[rep][bin], pq);
        }
        if (pos){
            pc++;
            const float4 G = sg[bg[j]];
            float axc = (ax[j] + az[j]) * 0.5f, ayc = (Ay + Ay2) * 0.5f;
            float aw = fmaxf(az[j] - ax[j], 1e-6f), ah = fmaxf(Ay2 - Ay, 1e-6f);
            float gxc = (G.x + G.z) * 0.5f, gyc = (G.y + G.w) * 0.5f;
            float gw = fmaxf(G.z - G.x, 1e-6f), gh = fmaxf(G.w - G.y, 1e-6f);
            float p0 = pp[0 * cP + j];
            float p1 = pp[1 * cP + j];
            float p2 = pp[2 * cP + j];
            float p3 = pp[3 * cP + j];
            loss += smooth_l1(p0 - (gxc - axc) / aw);
            loss += smooth_l1(p1 - (gyc - ayc) / ah);
            loss += smooth_l1(p2 - logf(gw / aw));
            loss += smooth_l1(p3 - logf(gh / ah));
            loss += bce_logits(p4a[j], 1.f);
            float c0 = pp[5 * cP + j];
            float c1 = pp[6 * cP + j];
            float c2 = pp[7 * cP + j];
            float m = fmaxf(c0, fmaxf(c1, c2));
            float lse = m + logf(expf(c0 - m) + expf(c1 - m) + expf(c2 - m));
            int tg = sl[bg[j]];
            float ct = (tg == 0) ? c0 : ((tg == 1) ? c1 : c2);
            loss += lse - ct;
        }
    }

    // per-wave loss reduce (register-only), then one sync covers
    // {LDS atomics done, wsum visible} for both flush and slot write.
    for (int off = 32; off > 0; off >>= 1){
        loss += __shfl_down(loss, off);
        pc   += __shfl_down(pc, off);
    }
    __shared__ float wsum[BLK / 64];
    __shared__ int   wcnt[BLK / 64];
    if ((tid & 63) == 0){ wsum[tid >> 6] = loss; wcnt[tid >> 6] = pc; }
    __syncthreads();

    // flush nonzero bins to the per-slice global histogram
    unsigned long long* gh = hist + (size_t)(s * B + b) * NBINS;
    for (int i = tid; i < NBINS; i += BLK){
        unsigned long long t = sh_h[0][i] + sh_h[1][i];
        if (t) atomicAdd(&gh[i], t);
    }

    if (tid == 0){
        float S = 0.f; int C = 0;
        for (int i = 0; i < BLK / 64; ++i){ S += wsum[i]; C += wcnt[i]; }
        loss_slot[b * 63 + bx] = S;
        pcnt_slot[b * 63 + bx] = C;
        if (b == 0 && bx == 0) *done_cnt = 0u;   // visible to select via stream order
    }
}

// One 1024-thread block per (scale,image). Histogram is already built:
// just read 2048 packed bins, descending prefix over 2 bins/thread,
// closed-form top-K sum:
//   sum = aboveQ*2^-22 + rem * binLowerBound   (error <= rem*2^-9, << tol).
// Then slice slot + ticket; last block reduces all slices -> out.
__global__ __launch_bounds__(SBLK)
void det_select(const unsigned long long* __restrict__ hist,
                const float* __restrict__ loss_slot,
                const int* __restrict__ pcnt_slot,
                double* __restrict__ slice_tot,   // 3*B
                unsigned* __restrict__ done_cnt,
                float* __restrict__ out, int B)
{
    const int sb = blockIdx.x;
    const int s = sb / B, b = sb - s * B;

    const int tid = threadIdx.x;
    const int lane = tid & 63, w = tid >> 6;

    __shared__ unsigned long long waveT[16];
    __shared__ unsigned long long waveOff[17];
    __shared__ double sh_sel;
    __shared__ float sh_ml;
    __shared__ int sh_done, sh_K, sh_last;

    // ---- sum this slice's per-block map loss / pos count (wave 0) ----
    {
        const int nb   = (s == 0) ? 48 : (s == 1) ? 12 : 3;
        const int off0 = b * 63 + ((s == 0) ? 0 : (s == 1) ? 48 : 60);
        float ml = 0.f; int C = 0;
        if (tid < nb){ ml = loss_slot[off0 + tid]; C = pcnt_slot[off0 + tid]; }
        if (tid < 64){
            for (int off = 32; off > 0; off >>= 1){
                ml += __shfl_down(ml, off);
                C  += __shfl_down(C, off);
            }
            if (tid == 0){ sh_ml = ml; sh_K = 3 * max(1, C); sh_done = 0; }
        }
    }

    // ---- descending prefix over 2 bins/thread; closed-form top-K sum ----
    const int bhi = NBINS - 1 - 2 * tid;
    const unsigned long long c0p = hist[(size_t)sb * NBINS + bhi];
    const unsigned long long c1p = hist[(size_t)sb * NBINS + bhi - 1];
    const unsigned long long pair = c0p + c1p;
    unsigned long long ci = pair;
    #pragma unroll
    for (int off = 1; off < 64; off <<= 1){
        unsigned long long cu = __shfl_up(ci, off);
        if (lane >= off) ci += cu;
    }
    if (lane == 63) waveT[w] = ci;
    __syncthreads();
    if (tid == 0){
        unsigned long long acc = 0ULL;
        #pragma unroll
        for (int i = 0; i < 16; ++i){ waveOff[i] = acc; acc += waveT[i]; }
        waveOff[16] = acc;
        if (sh_K >= (int)(acc >> CSH)){          // keep all negatives
            sh_done = 1;
            sh_sel = (double)(acc & QMASK) * (1.0 / 4194304.0);
        }
    }
    __syncthreads();

    if (!sh_done){
        const int K = sh_K;
        const unsigned long long giP = waveOff[w] + ci;
        const unsigned long long geP = giP - pair;
        const int gi = (int)(giP >> CSH);
        const int ge = (int)(geP >> CSH);
        if (ge < K && K <= gi){
            const int c0 = (int)(c0p >> CSH);
            int bin, aboveC; unsigned long long aboveQ;
            if (ge + c0 >= K){ bin = bhi;     aboveC = ge;      aboveQ = geP & QMASK; }
            else             { bin = bhi - 1; aboveC = ge + c0; aboveQ = (geP + c0p) & QMASK; }
            float thresh = (float)bin * (1.f / 512.f);
            sh_sel = (double)aboveQ * (1.0 / 4194304.0)
                   + (double)(K - aboveC) * (double)thresh;
        }
        __syncthreads();
    }

    // ---- slice total -> slot; last ticket block reduces all slices ----
    if (tid == 0){
        slice_tot[sb] = (double)sh_ml + sh_sel;
        __threadfence();
        unsigned t = atomicAdd(done_cnt, 1u);
        sh_last = (t == (unsigned)(gridDim.x - 1));
        if (sh_last) __threadfence();
    }
    __syncthreads();
    if (sh_last){
        double p = (tid < 3 * B) ? slice_tot[tid] : 0.0;
        for (int off = 32; off > 0; off >>= 1) p += __shfl_down(p, off);
        __shared__ double wred[16];
        if (lane == 0) wred[w] = p;
        __syncthreads();
        if (tid == 0){
            double tot = 0.0;
            for (int i = 0; i < 16; ++i) tot += wred[i];
            out[0] = (float)(tot / (double)B);
        }
    }
}

extern "C" void kernel_launch(void* const* d_in, const int* in_sizes, int n_in,
                              void* d_out, int out_size, void* d_ws, size_t ws_size,
                              hipStream_t stream)
{
    const float* gtb = (const float*)d_in[6];
    const int*   gtl = (const int*)d_in[7];
    const int B = in_sizes[6] / (32 * 4);   // 64

    unsigned* done      = (unsigned*)d_ws;                         // @0
    double*   slice_tot = (double*)((char*)d_ws + 64);             // 192 doubles
    float*    loss_slot = (float*)((char*)d_ws + 2048);            // 63*B floats
    int*      pcnt_slot = (int*)((char*)d_ws + 2048 + 16384);      // 63*B ints
    unsigned long long* hist = (unsigned long long*)((char*)d_ws + 36864); // 3*B*2048 u64

    hipMemsetAsync(hist, 0, (size_t)(3 * B) * NBINS * sizeof(unsigned long long), stream);
    det_map_all<<<dim3(63, B), BLK, 0, stream>>>(
        (const float*)d_in[0], (const float*)d_in[2], (const float*)d_in[4],
        gtb, gtl, hist, loss_slot, pcnt_slot, done, B);
    det_select<<<dim3(3 * B), SBLK, 0, stream>>>(
        hist, loss_slot, pcnt_slot, slice_tot, done, (float*)d_out, B);
}